// Round 1
// baseline (1366.338 us; speedup 1.0000x reference)
//
#include <hip/hip_runtime.h>
#include <stdint.h>

// Problem dims
#define Bdim 32
#define Ndim 4096
#define Cin  64
#define Cout 64
#define Demb 16
#define Jdim 2048                  // B*Cin columns of the big GEMM

typedef __bf16 bf16x8 __attribute__((ext_vector_type(8)));
typedef float  f32x4  __attribute__((ext_vector_type(4)));

#define GLOBAL_AS(p) ((__attribute__((address_space(1))) void*)(p))
#define LDS_AS(p)    ((__attribute__((address_space(3))) void*)(p))

__device__ __forceinline__ uint16_t f2bf(float x) {
    union { float f; uint32_t u; } v; v.f = x;
    uint32_t r = v.u + 0x7FFFu + ((v.u >> 16) & 1u);   // RNE, finite inputs
    return (uint16_t)(r >> 16);
}

__device__ __forceinline__ void unpack8(uint4 v, float* f) {
    const uint32_t* pu = (const uint32_t*)&v;
#pragma unroll
    for (int q = 0; q < 4; ++q) {
        union { uint32_t u; float f; } lo, hi;
        lo.u = pu[q] << 16;
        hi.u = pu[q] & 0xffff0000u;
        f[q * 2 + 0] = lo.f;
        f[q * 2 + 1] = hi.f;
    }
}

// ---------------------------------------------------------------------------
// K1: A[n][m] = softmax_m(relu(E[n]·E[m])), bf16 out.  grid 256, block 256.
// Block owns 16 rows; 2 groups of 8 rows held in registers; no max-subtract
// (relu(E·E) <= ~60, exp fits fp32 comfortably).
// ---------------------------------------------------------------------------
__global__ __launch_bounds__(256) void k1_dyn_adj(const float* __restrict__ E,
                                                  uint16_t* __restrict__ A) {
    const int t = threadIdx.x;
    const int n0 = blockIdx.x * 16;
    __shared__ float Er_s[16][16];
    __shared__ float red_s[4];
    __shared__ float inv_s[8];

    Er_s[t >> 4][t & 15] = E[(n0 + (t >> 4)) * Demb + (t & 15)];
    __syncthreads();

    for (int half = 0; half < 2; ++half) {
        float er[8][16];
#pragma unroll
        for (int r = 0; r < 8; ++r)
#pragma unroll
            for (int d = 0; d < 16; ++d) er[r][d] = Er_s[half * 8 + r][d];

        float sacc[8];
#pragma unroll
        for (int r = 0; r < 8; ++r) sacc[r] = 0.f;

        for (int c = 0; c < 16; ++c) {
            const int m = c * 256 + t;
            const float4* ep = (const float4*)(E + (size_t)m * Demb);
            float4 e0 = ep[0], e1 = ep[1], e2 = ep[2], e3 = ep[3];
            float em[16] = {e0.x, e0.y, e0.z, e0.w, e1.x, e1.y, e1.z, e1.w,
                            e2.x, e2.y, e2.z, e2.w, e3.x, e3.y, e3.z, e3.w};
#pragma unroll
            for (int r = 0; r < 8; ++r) {
                float v = 0.f;
#pragma unroll
                for (int d = 0; d < 16; ++d) v = fmaf(er[r][d], em[d], v);
                v = fmaxf(v, 0.f);
                sacc[r] += __expf(v);
            }
        }
#pragma unroll
        for (int r = 0; r < 8; ++r) {
            float s = sacc[r];
#pragma unroll
            for (int off = 32; off > 0; off >>= 1) s += __shfl_down(s, off, 64);
            __syncthreads();
            if ((t & 63) == 0) red_s[t >> 6] = s;
            __syncthreads();
            if (t == 0) inv_s[r] = 1.f / (red_s[0] + red_s[1] + red_s[2] + red_s[3]);
        }
        __syncthreads();
        float inv[8];
#pragma unroll
        for (int r = 0; r < 8; ++r) inv[r] = inv_s[r];

        for (int c = 0; c < 16; ++c) {
            const int m = c * 256 + t;
            const float4* ep = (const float4*)(E + (size_t)m * Demb);
            float4 e0 = ep[0], e1 = ep[1], e2 = ep[2], e3 = ep[3];
            float em[16] = {e0.x, e0.y, e0.z, e0.w, e1.x, e1.y, e1.z, e1.w,
                            e2.x, e2.y, e2.z, e2.w, e3.x, e3.y, e3.z, e3.w};
#pragma unroll
            for (int r = 0; r < 8; ++r) {
                float v = 0.f;
#pragma unroll
                for (int d = 0; d < 16; ++d) v = fmaf(er[r][d], em[d], v);
                v = fmaxf(v, 0.f);
                A[(size_t)(n0 + half * 8 + r) * Ndim + m] = f2bf(__expf(v) * inv[r]);
            }
        }
        __syncthreads();
    }
}

// ---------------------------------------------------------------------------
// K2: Xtt[j = b*64+c][m] = bf16(x[b][m][c]).  grid (64 mtiles, 32 b), 256 thr.
// LDS tile transpose, 72-element (144B) padded rows so uint4 reads stay aligned.
// ---------------------------------------------------------------------------
__global__ __launch_bounds__(256) void k2_transpose(const float* __restrict__ x,
                                                    uint16_t* __restrict__ Xtt) {
    __shared__ __align__(16) uint16_t T[64][72];
    const int t = threadIdx.x;
    const int m0 = blockIdx.x * 64;
    const int b = blockIdx.y;
    const int c = t & 63;
#pragma unroll
    for (int j = 0; j < 16; ++j) {
        const int m = (t >> 6) + j * 4;
        T[c][m] = f2bf(x[((size_t)b * Ndim + (m0 + m)) * Cin + c]);
    }
    __syncthreads();
    const int c2 = t >> 2, mo = (t & 3) * 16;
    const uint4* src = (const uint4*)&T[c2][mo];
    uint4 v0 = src[0], v1 = src[1];
    uint4* dst = (uint4*)(Xtt + (size_t)(b * Cin + c2) * Ndim + m0 + mo);
    dst[0] = v0;
    dst[1] = v1;
}

// ---------------------------------------------------------------------------
// K3: XG[n][j] = sum_m A[n][m] * Xtt[j][m]   (4096 x 2048 x 4096, bf16->f32->bf16)
// m97-style: 128x128 block tile, BK=32, 4 waves (2x2), 4x4 16x16x32 MFMA/wave,
// global_load_lds width=16 staging, XOR chunk swizzle (2-way-free ds_read_b128).
// grid (16, 32), 256 threads.
// ---------------------------------------------------------------------------
#define GK 4096
#define GN 2048
__global__ __launch_bounds__(256) void k3_gemm(const uint16_t* __restrict__ Abf,
                                               const uint16_t* __restrict__ Bbf,
                                               uint16_t* __restrict__ Cbf) {
    __shared__ __align__(16) uint16_t As[128 * 32];
    __shared__ __align__(16) uint16_t Bs[128 * 32];
    const int t = threadIdx.x;
    const int lane = t & 63;
    const int w = t >> 6;
    const int wr = w >> 1, wc = w & 1;
    const int bm = blockIdx.y * 128;
    const int bn = blockIdx.x * 128;

    f32x4 acc[4][4];
#pragma unroll
    for (int i = 0; i < 4; ++i)
#pragma unroll
        for (int j = 0; j < 4; ++j) acc[i][j] = (f32x4){0.f, 0.f, 0.f, 0.f};

    const uint16_t* agp[2];
    const uint16_t* bgp[2];
    uint16_t* alp[2];
    uint16_t* blp[2];
#pragma unroll
    for (int i = 0; i < 2; ++i) {
        const int r = w * 32 + i * 16 + (lane >> 2);
        const int cg = (lane & 3) ^ ((r >> 1) & 3);      // fetch swizzled chunk
        agp[i] = Abf + (size_t)(bm + r) * GK + cg * 8;
        bgp[i] = Bbf + (size_t)(bn + r) * GK + cg * 8;
        alp[i] = &As[(w * 32 + i * 16) * 32];
        blp[i] = &Bs[(w * 32 + i * 16) * 32];
    }

    int offA[4], offB[4];
#pragma unroll
    for (int i = 0; i < 4; ++i) {
        const int m = wr * 64 + i * 16 + (lane & 15);
        offA[i] = m * 32 + (((lane >> 4) ^ ((m >> 1) & 3)) * 8);
        const int n = wc * 64 + i * 16 + (lane & 15);
        offB[i] = n * 32 + (((lane >> 4) ^ ((n >> 1) & 3)) * 8);
    }

    for (int kt = 0; kt < GK / 32; ++kt) {
#pragma unroll
        for (int i = 0; i < 2; ++i) {
            __builtin_amdgcn_global_load_lds(GLOBAL_AS(agp[i] + (size_t)kt * 32), LDS_AS(alp[i]), 16, 0, 0);
            __builtin_amdgcn_global_load_lds(GLOBAL_AS(bgp[i] + (size_t)kt * 32), LDS_AS(blp[i]), 16, 0, 0);
        }
        __syncthreads();
        bf16x8 af[4], bfr[4];
#pragma unroll
        for (int i = 0; i < 4; ++i) {
            af[i] = *(const bf16x8*)(As + offA[i]);
            bfr[i] = *(const bf16x8*)(Bs + offB[i]);
        }
#pragma unroll
        for (int i = 0; i < 4; ++i)
#pragma unroll
            for (int j = 0; j < 4; ++j)
                acc[i][j] = __builtin_amdgcn_mfma_f32_16x16x32_bf16(af[i], bfr[j], acc[i][j], 0, 0, 0);
        __syncthreads();
    }
#pragma unroll
    for (int i = 0; i < 4; ++i)
#pragma unroll
        for (int j = 0; j < 4; ++j)
#pragma unroll
            for (int r = 0; r < 4; ++r) {
                const int row = bm + wr * 64 + i * 16 + (lane >> 4) * 4 + r;
                const int col = bn + wc * 64 + j * 16 + (lane & 15);
                Cbf[(size_t)row * GN + col] = f2bf(acc[i][j][r]);
            }
}

// ---------------------------------------------------------------------------
// K4a: sd[n] = sqrt(1/(rowsum(adj[n]) + 0.5)); also zero `scale`.
// grid 4096, block 256.
// ---------------------------------------------------------------------------
__global__ __launch_bounds__(256) void k4a_rowsum(const float* __restrict__ adj,
                                                  float* __restrict__ sd,
                                                  float* __restrict__ scale) {
    const int t = threadIdx.x;
    const int n = blockIdx.x;
    const int gid = blockIdx.x * 256 + t;
    if (gid < Ndim) scale[gid] = 0.f;
    __shared__ float red_s[4];
    const float4* ap = (const float4*)(adj + (size_t)n * Ndim);
    float s = 0.f;
#pragma unroll
    for (int q = 0; q < 4; ++q) {
        float4 a = ap[q * 256 + t];
        s += a.x + a.y + a.z + a.w;
    }
#pragma unroll
    for (int off = 32; off > 0; off >>= 1) s += __shfl_down(s, off, 64);
    if ((t & 63) == 0) red_s[t >> 6] = s;
    __syncthreads();
    if (t == 0) sd[n] = sqrtf(1.f / (red_s[0] + red_s[1] + red_s[2] + red_s[3] + 0.5f));
}

__device__ __forceinline__ float block_reduce(float v, float* red_s, int t, bool domax) {
#pragma unroll
    for (int off = 32; off > 0; off >>= 1) {
        float o = __shfl_down(v, off, 64);
        v = domax ? fmaxf(v, o) : (v + o);
    }
    __syncthreads();
    if ((t & 63) == 0) red_s[t >> 6] = v;
    __syncthreads();
    return domax ? fmaxf(fmaxf(red_s[0], red_s[1]), fmaxf(red_s[2], red_s[3]))
                 : (red_s[0] + red_s[1] + red_s[2] + red_s[3]);
}

// ---------------------------------------------------------------------------
// K4b: scale[m] = sum_n softmax_row(softmax_row(sd*(adj+0.5I)*sd))[n][m]
// grid 256 (16 rows each), block 256; thread privately owns 16 columns.
// ---------------------------------------------------------------------------
__global__ __launch_bounds__(256) void k4b_scale(const float* __restrict__ adj,
                                                 const float* __restrict__ sd,
                                                 float* __restrict__ scale) {
    const int t = threadIdx.x;
    const int nb = blockIdx.x * 16;
    __shared__ float red_s[4];
    float sdm[16], colsum[16];
#pragma unroll
    for (int q = 0; q < 4; ++q) {
        float4 v = *(const float4*)(sd + q * 1024 + t * 4);
        sdm[q * 4 + 0] = v.x; sdm[q * 4 + 1] = v.y;
        sdm[q * 4 + 2] = v.z; sdm[q * 4 + 3] = v.w;
        colsum[q * 4 + 0] = colsum[q * 4 + 1] = colsum[q * 4 + 2] = colsum[q * 4 + 3] = 0.f;
    }
    for (int r = 0; r < 16; ++r) {
        const int n = nb + r;
        const float sdn = sd[n];
        float v[16];
#pragma unroll
        for (int q = 0; q < 4; ++q) {
            float4 a = *(const float4*)(adj + (size_t)n * Ndim + q * 1024 + t * 4);
            const int mb = q * 1024 + t * 4;
            v[q * 4 + 0] = a.x + ((mb + 0) == n ? 0.5f : 0.f);
            v[q * 4 + 1] = a.y + ((mb + 1) == n ? 0.5f : 0.f);
            v[q * 4 + 2] = a.z + ((mb + 2) == n ? 0.5f : 0.f);
            v[q * 4 + 3] = a.w + ((mb + 3) == n ? 0.5f : 0.f);
        }
        float mx = -1e30f;
#pragma unroll
        for (int i = 0; i < 16; ++i) { v[i] = sdn * v[i] * sdm[i]; mx = fmaxf(mx, v[i]); }
        mx = block_reduce(mx, red_s, t, true);
        float s1 = 0.f;
#pragma unroll
        for (int i = 0; i < 16; ++i) { v[i] = __expf(v[i] - mx); s1 += v[i]; }
        s1 = block_reduce(s1, red_s, t, false);
        const float inv1 = 1.f / s1;
        float s2 = 0.f;
#pragma unroll
        for (int i = 0; i < 16; ++i) { v[i] = __expf(v[i] * inv1); s2 += v[i]; }
        s2 = block_reduce(s2, red_s, t, false);
        const float inv2 = 1.f / s2;
#pragma unroll
        for (int i = 0; i < 16; ++i) colsum[i] += v[i] * inv2;
    }
#pragma unroll
    for (int q = 0; q < 4; ++q)
#pragma unroll
        for (int u = 0; u < 4; ++u)
            atomicAdd(scale + q * 1024 + t * 4 + u, colsum[q * 4 + u]);
}

// ---------------------------------------------------------------------------
// K5: Wall[n][k][i][o] = bf16(sum_d E[n,d]*pool[d,k,i,o]); biasn[n][o] f32.
// grid 256 (16 nodes), block 256 as 2 groups x 128 threads x 8 nodes each
// (E rows in registers so pool reads amortize over 8 nodes).
// ---------------------------------------------------------------------------
__global__ __launch_bounds__(256) void k5_wgen(const float* __restrict__ E,
                                               const float* __restrict__ pool,
                                               const float* __restrict__ bias_pool,
                                               uint16_t* __restrict__ Wall,
                                               float* __restrict__ biasn) {
    const int t = threadIdx.x;
    const int n0 = blockIdx.x * 16;
    __shared__ float En[16][16];
    En[t >> 4][t & 15] = E[(n0 + (t >> 4)) * Demb + (t & 15)];
    __syncthreads();
    const int grp = t >> 7;
    const int lt = t & 127;
    const int nb = grp * 8;
    float en[8][16];
#pragma unroll
    for (int g = 0; g < 8; ++g)
#pragma unroll
        for (int d = 0; d < 16; ++d) en[g][d] = En[nb + g][d];
    for (int ii = 0; ii < 64; ++ii) {
        const int idx = ii * 128 + lt;
        float p[16];
#pragma unroll
        for (int d = 0; d < 16; ++d) p[d] = pool[d * 8192 + idx];
#pragma unroll
        for (int g = 0; g < 8; ++g) {
            float a = 0.f;
#pragma unroll
            for (int d = 0; d < 16; ++d) a = fmaf(en[g][d], p[d], a);
            Wall[(size_t)(n0 + nb + g) * 8192 + idx] = f2bf(a);
        }
    }
    if (t < 64) {
        for (int g = 0; g < 16; ++g) {
            float a = 0.f;
#pragma unroll
            for (int d = 0; d < 16; ++d) a += En[g][d] * bias_pool[d * 64 + t];
            biasn[(size_t)(n0 + g) * 64 + t] = a;
        }
    }
}

// ---------------------------------------------------------------------------
// K6: out[b][n][o] = (sum_ki xg[b,n,ki]*W[n,ki,o] + biasn[n,o])
//                    + silu_gate(scale[n]*(x[b,n]·lin_w[o]) + lin_b[o])
// grid 1024 (4 nodes/block, 1 wave per node), block 256.
// LDS images: W2s[g][oo][og][i+pad] bf16 (per k-half), XGs[g][b][i+pad] bf16,
// Ls = lin_w image. Thread tile: 8 b x 4 o, f32 accumulate.
// ---------------------------------------------------------------------------
__global__ __launch_bounds__(256) void k6_gconv(const float* __restrict__ x,
                                                const uint16_t* __restrict__ XG,
                                                const uint16_t* __restrict__ Wall,
                                                const float* __restrict__ biasn,
                                                const float* __restrict__ scale,
                                                const float* __restrict__ lin_w,
                                                const float* __restrict__ lin_b,
                                                float* __restrict__ out) {
    const int t = threadIdx.x;
    const int n0 = blockIdx.x * 4;
    __shared__ __align__(16) uint16_t W2s[4][4][16][72];
    __shared__ __align__(16) uint16_t XGs[4][32][72];
    __shared__ __align__(16) uint16_t Ls[4][16][72];

    const int g = t >> 6;            // wave == node group
    const int pos = t & 63;
    const int og = pos & 15;         // o = og*4 + oo
    const int bg = pos >> 4;         // b = bg*8 + bi

    float accg[8][4], accs[8][4];
#pragma unroll
    for (int bi = 0; bi < 8; ++bi)
#pragma unroll
        for (int oo = 0; oo < 4; ++oo) { accg[bi][oo] = 0.f; accs[bi][oo] = 0.f; }

    // stage lin_w image (block-wide, once)
#pragma unroll
    for (int j = 0; j < 4; ++j) {
        const int e4 = j * 256 + t;
        const int o = e4 >> 4, i4 = (e4 & 15) * 4;
        float4 wv = *(const float4*)(lin_w + o * 64 + i4);
        Ls[o & 3][o >> 2][i4 + 0] = f2bf(wv.x);
        Ls[o & 3][o >> 2][i4 + 1] = f2bf(wv.y);
        Ls[o & 3][o >> 2][i4 + 2] = f2bf(wv.z);
        Ls[o & 3][o >> 2][i4 + 3] = f2bf(wv.w);
    }

    for (int kh = 0; kh < 2; ++kh) {
        if (kh) __syncthreads();     // protect LDS before restage
        // stage W plane kh for all 4 nodes
#pragma unroll
        for (int j = 0; j < 8; ++j) {
            const int e8 = j * 256 + t;              // 2048 x 8 elems
            const int gg = e8 >> 9;
            const int idx8 = (e8 & 511) * 8;
            uint4 v = *(const uint4*)(Wall + (size_t)(n0 + gg) * 8192 + kh * 4096 + idx8);
            const uint16_t* pv = (const uint16_t*)&v;
            const int i = idx8 >> 6;
            const int ob = idx8 & 63;
#pragma unroll
            for (int u = 0; u < 8; ++u) {
                const int o = ob + u;
                W2s[gg][o & 3][o >> 2][i] = pv[u];
            }
        }
        if (kh == 0) {
            // xg half 0 = x[b][n][i], f32 -> bf16
#pragma unroll
            for (int j = 0; j < 8; ++j) {
                const int e4 = j * 256 + t;          // 2048 x 4 elems
                const int gg = e4 >> 9;
                const int r = e4 & 511;
                const int bb = r >> 4, i4 = (r & 15) * 4;
                float4 xv = *(const float4*)(x + ((size_t)bb * Ndim + (n0 + gg)) * 64 + i4);
                XGs[gg][bb][i4 + 0] = f2bf(xv.x);
                XGs[gg][bb][i4 + 1] = f2bf(xv.y);
                XGs[gg][bb][i4 + 2] = f2bf(xv.z);
                XGs[gg][bb][i4 + 3] = f2bf(xv.w);
            }
        } else {
            // xg half 1 = XG[n][b*64+i], already bf16
#pragma unroll
            for (int j = 0; j < 4; ++j) {
                const int e8 = j * 256 + t;          // 1024 x 8 elems
                const int gg = e8 >> 8;
                const int r8 = (e8 & 255) * 8;
                uint4 v = *(const uint4*)(XG + (size_t)(n0 + gg) * 2048 + r8);
                const int bb = r8 >> 6, i0 = r8 & 63;
                *(uint4*)&XGs[gg][bb][i0] = v;
            }
        }
        __syncthreads();
        // compute
#pragma unroll
        for (int ch = 0; ch < 8; ++ch) {
            const int i0 = ch * 8;
            float xv[8][8];
#pragma unroll
            for (int bi = 0; bi < 8; ++bi) {
                uint4 xf = *(const uint4*)&XGs[g][bg * 8 + bi][i0];
                unpack8(xf, xv[bi]);
            }
#pragma unroll
            for (int oo = 0; oo < 4; ++oo) {
                uint4 wf = *(const uint4*)&W2s[g][oo][og][i0];
                float wv[8];
                unpack8(wf, wv);
#pragma unroll
                for (int bi = 0; bi < 8; ++bi) {
                    float a = accg[bi][oo];
#pragma unroll
                    for (int u = 0; u < 8; ++u) a = fmaf(xv[bi][u], wv[u], a);
                    accg[bi][oo] = a;
                }
            }
            if (kh == 0) {
#pragma unroll
                for (int oo = 0; oo < 4; ++oo) {
                    uint4 lf = *(const uint4*)&Ls[oo][og][i0];
                    float lv[8];
                    unpack8(lf, lv);
#pragma unroll
                    for (int bi = 0; bi < 8; ++bi) {
                        float a = accs[bi][oo];
#pragma unroll
                        for (int u = 0; u < 8; ++u) a = fmaf(xv[bi][u], lv[u], a);
                        accs[bi][oo] = a;
                    }
                }
            }
        }
    }
    // epilogue
    const int n = n0 + g;
    const float sc = scale[n];
    float4 bnv = *(const float4*)(biasn + (size_t)n * 64 + og * 4);
    float4 lbv = *(const float4*)(lin_b + og * 4);
#pragma unroll
    for (int bi = 0; bi < 8; ++bi) {
        const int b = bg * 8 + bi;
        float4 o4;
        float xs;
        xs = sc * accs[bi][0] + lbv.x; o4.x = accg[bi][0] + bnv.x + xs / (1.f + __expf(-xs));
        xs = sc * accs[bi][1] + lbv.y; o4.y = accg[bi][1] + bnv.y + xs / (1.f + __expf(-xs));
        xs = sc * accs[bi][2] + lbv.z; o4.z = accg[bi][2] + bnv.z + xs / (1.f + __expf(-xs));
        xs = sc * accs[bi][3] + lbv.w; o4.w = accg[bi][3] + bnv.w + xs / (1.f + __expf(-xs));
        *(float4*)(out + ((size_t)b * Ndim + n) * 64 + og * 4) = o4;
    }
}

// ---------------------------------------------------------------------------
extern "C" void kernel_launch(void* const* d_in, const int* in_sizes, int n_in,
                              void* d_out, int out_size, void* d_ws, size_t ws_size,
                              hipStream_t stream) {
    const float* x         = (const float*)d_in[0];
    const float* E         = (const float*)d_in[1];
    const float* pool      = (const float*)d_in[2];
    const float* bias_pool = (const float*)d_in[3];
    const float* lin_w     = (const float*)d_in[4];
    const float* lin_b     = (const float*)d_in[5];
    const float* adj       = (const float*)d_in[6];
    float* out = (float*)d_out;

    uint8_t* ws = (uint8_t*)d_ws;
    uint16_t* A     = (uint16_t*)(ws);                 // 4096*4096*2  = 32 MiB
    uint16_t* Xtt   = (uint16_t*)(ws + 33554432);      // 2048*4096*2  = 16 MiB
    uint16_t* XG    = (uint16_t*)(ws + 50331648);      // 4096*2048*2  = 16 MiB
    uint16_t* Wall  = (uint16_t*)(ws + 67108864);      // 4096*8192*2  = 64 MiB
    float*    biasn = (float*)   (ws + 134217728);     // 4096*64*4    = 1 MiB
    float*    sd    = (float*)   (ws + 135266304);     // 16 KiB
    float*    scale = (float*)   (ws + 135282688);     // 16 KiB

    k1_dyn_adj<<<dim3(256), dim3(256), 0, stream>>>(E, A);
    k2_transpose<<<dim3(64, 32), dim3(256), 0, stream>>>(x, Xtt);
    k4a_rowsum<<<dim3(4096), dim3(256), 0, stream>>>(adj, sd, scale);
    k4b_scale<<<dim3(256), dim3(256), 0, stream>>>(adj, sd, scale);
    k5_wgen<<<dim3(256), dim3(256), 0, stream>>>(E, pool, bias_pool, Wall, biasn);
    k3_gemm<<<dim3(16, 32), dim3(256), 0, stream>>>(A, Xtt, XG);
    k6_gconv<<<dim3(1024), dim3(256), 0, stream>>>(x, XG, Wall, biasn, scale, lin_w, lin_b, out);
}

// Round 2
// 544.250 us; speedup vs baseline: 2.5105x; 2.5105x over previous
//
#include <hip/hip_runtime.h>
#include <stdint.h>

// Problem dims
#define Bdim 32
#define Ndim 4096
#define Cin  64
#define Cout 64
#define Demb 16

typedef __bf16 bf16x8 __attribute__((ext_vector_type(8)));
typedef float  f32x4  __attribute__((ext_vector_type(4)));

#define GLOBAL_AS(p) ((__attribute__((address_space(1))) void*)(p))
#define LDS_AS(p)    ((__attribute__((address_space(3))) void*)(p))

__device__ __forceinline__ uint16_t f2bf(float x) {
    union { float f; uint32_t u; } v; v.f = x;
    uint32_t r = v.u + 0x7FFFu + ((v.u >> 16) & 1u);   // RNE, finite inputs
    return (uint16_t)(r >> 16);
}

__device__ __forceinline__ bf16x8 pack8(float4 a, float4 b) {
    union { uint16_t u[8]; bf16x8 v; } r;
    r.u[0] = f2bf(a.x); r.u[1] = f2bf(a.y); r.u[2] = f2bf(a.z); r.u[3] = f2bf(a.w);
    r.u[4] = f2bf(b.x); r.u[5] = f2bf(b.y); r.u[6] = f2bf(b.z); r.u[7] = f2bf(b.w);
    return r.v;
}

// ---------------------------------------------------------------------------
// K1: A[n][m] = softmax_m(relu(E[n]·E[m])), bf16 out.  grid 256, block 256.
// ---------------------------------------------------------------------------
__global__ __launch_bounds__(256) void k1_dyn_adj(const float* __restrict__ E,
                                                  uint16_t* __restrict__ A) {
    const int t = threadIdx.x;
    const int n0 = blockIdx.x * 16;
    __shared__ float Er_s[16][16];
    __shared__ float red_s[4];
    __shared__ float inv_s[8];

    Er_s[t >> 4][t & 15] = E[(n0 + (t >> 4)) * Demb + (t & 15)];
    __syncthreads();

    for (int half = 0; half < 2; ++half) {
        float er[8][16];
#pragma unroll
        for (int r = 0; r < 8; ++r)
#pragma unroll
            for (int d = 0; d < 16; ++d) er[r][d] = Er_s[half * 8 + r][d];

        float sacc[8];
#pragma unroll
        for (int r = 0; r < 8; ++r) sacc[r] = 0.f;

        for (int c = 0; c < 16; ++c) {
            const int m = c * 256 + t;
            const float4* ep = (const float4*)(E + (size_t)m * Demb);
            float4 e0 = ep[0], e1 = ep[1], e2 = ep[2], e3 = ep[3];
            float em[16] = {e0.x, e0.y, e0.z, e0.w, e1.x, e1.y, e1.z, e1.w,
                            e2.x, e2.y, e2.z, e2.w, e3.x, e3.y, e3.z, e3.w};
#pragma unroll
            for (int r = 0; r < 8; ++r) {
                float v = 0.f;
#pragma unroll
                for (int d = 0; d < 16; ++d) v = fmaf(er[r][d], em[d], v);
                v = fmaxf(v, 0.f);
                sacc[r] += __expf(v);
            }
        }
#pragma unroll
        for (int r = 0; r < 8; ++r) {
            float s = sacc[r];
#pragma unroll
            for (int off = 32; off > 0; off >>= 1) s += __shfl_down(s, off, 64);
            __syncthreads();
            if ((t & 63) == 0) red_s[t >> 6] = s;
            __syncthreads();
            if (t == 0) inv_s[r] = 1.f / (red_s[0] + red_s[1] + red_s[2] + red_s[3]);
        }
        __syncthreads();
        float inv[8];
#pragma unroll
        for (int r = 0; r < 8; ++r) inv[r] = inv_s[r];

        for (int c = 0; c < 16; ++c) {
            const int m = c * 256 + t;
            const float4* ep = (const float4*)(E + (size_t)m * Demb);
            float4 e0 = ep[0], e1 = ep[1], e2 = ep[2], e3 = ep[3];
            float em[16] = {e0.x, e0.y, e0.z, e0.w, e1.x, e1.y, e1.z, e1.w,
                            e2.x, e2.y, e2.z, e2.w, e3.x, e3.y, e3.z, e3.w};
#pragma unroll
            for (int r = 0; r < 8; ++r) {
                float v = 0.f;
#pragma unroll
                for (int d = 0; d < 16; ++d) v = fmaf(er[r][d], em[d], v);
                v = fmaxf(v, 0.f);
                A[(size_t)(n0 + half * 8 + r) * Ndim + m] = f2bf(__expf(v) * inv[r]);
            }
        }
        __syncthreads();
    }
}

// ---------------------------------------------------------------------------
// K2: Xtt[j = b*64+c][m] = bf16(x[b][m][c]).  grid (64 mtiles, 32 b), 256 thr.
// ---------------------------------------------------------------------------
__global__ __launch_bounds__(256) void k2_transpose(const float* __restrict__ x,
                                                    uint16_t* __restrict__ Xtt) {
    __shared__ __align__(16) uint16_t T[64][72];
    const int t = threadIdx.x;
    const int m0 = blockIdx.x * 64;
    const int b = blockIdx.y;
    const int c = t & 63;
#pragma unroll
    for (int j = 0; j < 16; ++j) {
        const int m = (t >> 6) + j * 4;
        T[c][m] = f2bf(x[((size_t)b * Ndim + (m0 + m)) * Cin + c]);
    }
    __syncthreads();
    const int c2 = t >> 2, mo = (t & 3) * 16;
    const uint4* src = (const uint4*)&T[c2][mo];
    uint4 v0 = src[0], v1 = src[1];
    uint4* dst = (uint4*)(Xtt + (size_t)(b * Cin + c2) * Ndim + m0 + mo);
    dst[0] = v0;
    dst[1] = v1;
}

// ---------------------------------------------------------------------------
// K3: XG[n][j] = sum_m A[n][m] * Xtt[j][m]   (4096 x 2048 x 4096, bf16)
// ---------------------------------------------------------------------------
#define GK 4096
#define GN 2048
__global__ __launch_bounds__(256) void k3_gemm(const uint16_t* __restrict__ Abf,
                                               const uint16_t* __restrict__ Bbf,
                                               uint16_t* __restrict__ Cbf) {
    __shared__ __align__(16) uint16_t As[128 * 32];
    __shared__ __align__(16) uint16_t Bs[128 * 32];
    const int t = threadIdx.x;
    const int lane = t & 63;
    const int w = t >> 6;
    const int wr = w >> 1, wc = w & 1;
    const int bm = blockIdx.y * 128;
    const int bn = blockIdx.x * 128;

    f32x4 acc[4][4];
#pragma unroll
    for (int i = 0; i < 4; ++i)
#pragma unroll
        for (int j = 0; j < 4; ++j) acc[i][j] = (f32x4){0.f, 0.f, 0.f, 0.f};

    const uint16_t* agp[2];
    const uint16_t* bgp[2];
    uint16_t* alp[2];
    uint16_t* blp[2];
#pragma unroll
    for (int i = 0; i < 2; ++i) {
        const int r = w * 32 + i * 16 + (lane >> 2);
        const int cg = (lane & 3) ^ ((r >> 1) & 3);
        agp[i] = Abf + (size_t)(bm + r) * GK + cg * 8;
        bgp[i] = Bbf + (size_t)(bn + r) * GK + cg * 8;
        alp[i] = &As[(w * 32 + i * 16) * 32];
        blp[i] = &Bs[(w * 32 + i * 16) * 32];
    }

    int offA[4], offB[4];
#pragma unroll
    for (int i = 0; i < 4; ++i) {
        const int m = wr * 64 + i * 16 + (lane & 15);
        offA[i] = m * 32 + (((lane >> 4) ^ ((m >> 1) & 3)) * 8);
        const int n = wc * 64 + i * 16 + (lane & 15);
        offB[i] = n * 32 + (((lane >> 4) ^ ((n >> 1) & 3)) * 8);
    }

    for (int kt = 0; kt < GK / 32; ++kt) {
#pragma unroll
        for (int i = 0; i < 2; ++i) {
            __builtin_amdgcn_global_load_lds(GLOBAL_AS(agp[i] + (size_t)kt * 32), LDS_AS(alp[i]), 16, 0, 0);
            __builtin_amdgcn_global_load_lds(GLOBAL_AS(bgp[i] + (size_t)kt * 32), LDS_AS(blp[i]), 16, 0, 0);
        }
        __syncthreads();
        bf16x8 af[4], bfr[4];
#pragma unroll
        for (int i = 0; i < 4; ++i) {
            af[i] = *(const bf16x8*)(As + offA[i]);
            bfr[i] = *(const bf16x8*)(Bs + offB[i]);
        }
#pragma unroll
        for (int i = 0; i < 4; ++i)
#pragma unroll
            for (int j = 0; j < 4; ++j)
                acc[i][j] = __builtin_amdgcn_mfma_f32_16x16x32_bf16(af[i], bfr[j], acc[i][j], 0, 0, 0);
        __syncthreads();
    }
#pragma unroll
    for (int i = 0; i < 4; ++i)
#pragma unroll
        for (int j = 0; j < 4; ++j)
#pragma unroll
            for (int r = 0; r < 4; ++r) {
                const int row = bm + wr * 64 + i * 16 + (lane >> 4) * 4 + r;
                const int col = bn + wc * 64 + j * 16 + (lane & 15);
                Cbf[(size_t)row * GN + col] = f2bf(acc[i][j][r]);
            }
}

// ---------------------------------------------------------------------------
// K4a: sd[n] = sqrt(1/(rowsum(adj[n]) + 0.5)); also zero `scale`.
// ---------------------------------------------------------------------------
__global__ __launch_bounds__(256) void k4a_rowsum(const float* __restrict__ adj,
                                                  float* __restrict__ sd,
                                                  float* __restrict__ scale) {
    const int t = threadIdx.x;
    const int n = blockIdx.x;
    const int gid = blockIdx.x * 256 + t;
    if (gid < Ndim) scale[gid] = 0.f;
    __shared__ float red_s[4];
    const float4* ap = (const float4*)(adj + (size_t)n * Ndim);
    float s = 0.f;
#pragma unroll
    for (int q = 0; q < 4; ++q) {
        float4 a = ap[q * 256 + t];
        s += a.x + a.y + a.z + a.w;
    }
#pragma unroll
    for (int off = 32; off > 0; off >>= 1) s += __shfl_down(s, off, 64);
    if ((t & 63) == 0) red_s[t >> 6] = s;
    __syncthreads();
    if (t == 0) sd[n] = sqrtf(1.f / (red_s[0] + red_s[1] + red_s[2] + red_s[3] + 0.5f));
}

__device__ __forceinline__ float block_reduce(float v, float* red_s, int t, bool domax) {
#pragma unroll
    for (int off = 32; off > 0; off >>= 1) {
        float o = __shfl_down(v, off, 64);
        v = domax ? fmaxf(v, o) : (v + o);
    }
    __syncthreads();
    if ((t & 63) == 0) red_s[t >> 6] = v;
    __syncthreads();
    return domax ? fmaxf(fmaxf(red_s[0], red_s[1]), fmaxf(red_s[2], red_s[3]))
                 : (red_s[0] + red_s[1] + red_s[2] + red_s[3]);
}

// ---------------------------------------------------------------------------
// K4b: scale[m] = sum_n softmax_row(softmax_row(sd*(adj+0.5I)*sd))[n][m]
// ---------------------------------------------------------------------------
__global__ __launch_bounds__(256) void k4b_scale(const float* __restrict__ adj,
                                                 const float* __restrict__ sd,
                                                 float* __restrict__ scale) {
    const int t = threadIdx.x;
    const int nb = blockIdx.x * 16;
    __shared__ float red_s[4];
    float sdm[16], colsum[16];
#pragma unroll
    for (int q = 0; q < 4; ++q) {
        float4 v = *(const float4*)(sd + q * 1024 + t * 4);
        sdm[q * 4 + 0] = v.x; sdm[q * 4 + 1] = v.y;
        sdm[q * 4 + 2] = v.z; sdm[q * 4 + 3] = v.w;
        colsum[q * 4 + 0] = colsum[q * 4 + 1] = colsum[q * 4 + 2] = colsum[q * 4 + 3] = 0.f;
    }
    for (int r = 0; r < 16; ++r) {
        const int n = nb + r;
        const float sdn = sd[n];
        float v[16];
#pragma unroll
        for (int q = 0; q < 4; ++q) {
            float4 a = *(const float4*)(adj + (size_t)n * Ndim + q * 1024 + t * 4);
            const int mb = q * 1024 + t * 4;
            v[q * 4 + 0] = a.x + ((mb + 0) == n ? 0.5f : 0.f);
            v[q * 4 + 1] = a.y + ((mb + 1) == n ? 0.5f : 0.f);
            v[q * 4 + 2] = a.z + ((mb + 2) == n ? 0.5f : 0.f);
            v[q * 4 + 3] = a.w + ((mb + 3) == n ? 0.5f : 0.f);
        }
        float mx = -1e30f;
#pragma unroll
        for (int i = 0; i < 16; ++i) { v[i] = sdn * v[i] * sdm[i]; mx = fmaxf(mx, v[i]); }
        mx = block_reduce(mx, red_s, t, true);
        float s1 = 0.f;
#pragma unroll
        for (int i = 0; i < 16; ++i) { v[i] = __expf(v[i] - mx); s1 += v[i]; }
        s1 = block_reduce(s1, red_s, t, false);
        const float inv1 = 1.f / s1;
        float s2 = 0.f;
#pragma unroll
        for (int i = 0; i < 16; ++i) { v[i] = __expf(v[i] * inv1); s2 += v[i]; }
        s2 = block_reduce(s2, red_s, t, false);
        const float inv2 = 1.f / s2;
#pragma unroll
        for (int i = 0; i < 16; ++i) colsum[i] += v[i] * inv2;
    }
#pragma unroll
    for (int q = 0; q < 4; ++q)
#pragma unroll
        for (int u = 0; u < 4; ++u)
            atomicAdd(scale + q * 1024 + t * 4 + u, colsum[q * 4 + u]);
}

// ---------------------------------------------------------------------------
// K5: Wt[n][o][ki] = bf16(sum_d E[n,d]*pool[d][ki][o]); biasn[n][o] f32.
// TRANSPOSED output layout (o-major, ki-minor) so k6's MFMA B-fragments are
// contiguous along k.  grid 512 (8 nodes/block), block 256.
// Thread owns (o = t&63, kc = (t>>6)*4 + s); lanes consecutive in o so pool
// reads are 256B-coalesced; writes are 16B contiguous per (node, kc).
// ---------------------------------------------------------------------------
__global__ __launch_bounds__(256) void k5_wgen(const float* __restrict__ E,
                                               const float* __restrict__ pool,
                                               const float* __restrict__ bias_pool,
                                               uint16_t* __restrict__ Wt,
                                               float* __restrict__ biasn) {
    const int t = threadIdx.x;
    const int n0 = blockIdx.x * 8;
    __shared__ float En[8][16];
    if (t < 128) En[t >> 4][t & 15] = E[(n0 + (t >> 4)) * Demb + (t & 15)];
    __syncthreads();
    const int o = t & 63;
    const int kcb = (t >> 6) * 4;
    for (int s = 0; s < 4; ++s) {
        const int kc = kcb + s;
        float acc[8][8];
#pragma unroll
        for (int g = 0; g < 8; ++g)
#pragma unroll
            for (int j = 0; j < 8; ++j) acc[g][j] = 0.f;
#pragma unroll
        for (int d = 0; d < 16; ++d) {
            float p[8];
#pragma unroll
            for (int j = 0; j < 8; ++j) p[j] = pool[d * 8192 + (kc * 8 + j) * 64 + o];
#pragma unroll
            for (int g = 0; g < 8; ++g) {
                const float e = En[g][d];
#pragma unroll
                for (int j = 0; j < 8; ++j) acc[g][j] = fmaf(e, p[j], acc[g][j]);
            }
        }
#pragma unroll
        for (int g = 0; g < 8; ++g) {
            union { uint16_t u[8]; uint4 v; } r;
#pragma unroll
            for (int j = 0; j < 8; ++j) r.u[j] = f2bf(acc[g][j]);
            *(uint4*)(Wt + (size_t)(n0 + g) * 8192 + o * 128 + kc * 8) = r.v;
        }
    }
    if (t < 64) {
        for (int g = 0; g < 8; ++g) {
            float a = 0.f;
#pragma unroll
            for (int d = 0; d < 16; ++d) a += En[g][d] * bias_pool[d * 64 + t];
            biasn[(size_t)(n0 + g) * 64 + t] = a;
        }
    }
}

// ---------------------------------------------------------------------------
// K6 (MFMA rewrite): one wave per node n.
//   gconv:  D[b][o] = sum_{ki<128} xg[b][ki] * Wt[n][o][ki]   (2x4 tiles, K=4 steps)
//   static: S[b][o] = sum_{i<64}   x[b][n][i] * lin_w[o][i]   (2x4 tiles, K=2 steps)
// A-frags load straight from global (sector-efficient by construction);
// only Wt + lin_w are staged in LDS (padded rows: 2-way bank alias = free).
// Epilogue: out = D + biasn + silu(scale[n]*S + lin_b).
// grid 1024 (4 nodes/block), block 256, LDS 78848 B -> 2 blocks/CU.
// ---------------------------------------------------------------------------
__global__ __launch_bounds__(256) void k6_gconv(const float* __restrict__ x,
                                                const uint16_t* __restrict__ XG,
                                                const uint16_t* __restrict__ Wt,
                                                const float* __restrict__ biasn,
                                                const float* __restrict__ scale,
                                                const float* __restrict__ lin_w,
                                                const float* __restrict__ lin_b,
                                                float* __restrict__ out) {
    __shared__ __align__(16) uint16_t Ws[4][64][136];
    __shared__ __align__(16) uint16_t Lws[64][72];
    const int t = threadIdx.x;
    const int n0 = blockIdx.x * 4;

    // stage Wt for 4 nodes (64 KB, fully coalesced reads)
#pragma unroll
    for (int j = 0; j < 16; ++j) {
        const int e8 = (j * 256 + t) * 8;
        const int g = e8 >> 13;
        const int r = e8 & 8191;
        uint4 v = *(const uint4*)(Wt + (size_t)(n0 + g) * 8192 + r);
        *(uint4*)&Ws[g][r >> 7][r & 127] = v;
    }
    // stage lin_w as bf16
    {
        const int o = t >> 2, i0 = (t & 3) * 16;
        const float4* lp = (const float4*)(lin_w + o * 64 + i0);
        float4 a0 = lp[0], a1 = lp[1], a2 = lp[2], a3 = lp[3];
        union { uint16_t u[16]; uint4 v[2]; } r;
        r.u[0] = f2bf(a0.x); r.u[1] = f2bf(a0.y); r.u[2]  = f2bf(a0.z); r.u[3]  = f2bf(a0.w);
        r.u[4] = f2bf(a1.x); r.u[5] = f2bf(a1.y); r.u[6]  = f2bf(a1.z); r.u[7]  = f2bf(a1.w);
        r.u[8] = f2bf(a2.x); r.u[9] = f2bf(a2.y); r.u[10] = f2bf(a2.z); r.u[11] = f2bf(a2.w);
        r.u[12] = f2bf(a3.x); r.u[13] = f2bf(a3.y); r.u[14] = f2bf(a3.z); r.u[15] = f2bf(a3.w);
        *(uint4*)&Lws[o][i0] = r.v[0];
        *(uint4*)&Lws[o][i0 + 8] = r.v[1];
    }

    const int w = t >> 6, lane = t & 63;
    const int n = n0 + w;
    const int l15 = lane & 15;
    const int q8 = (lane >> 4) * 8;

    // A-fragments from global: ks 0,1 = x (f32->bf16), ks 2,3 = XG (bf16)
    bf16x8 a[2][4];
#pragma unroll
    for (int mt = 0; mt < 2; ++mt) {
        const int b = mt * 16 + l15;
        const float* xp = x + ((size_t)b * Ndim + n) * 64 + q8;
        a[mt][0] = pack8(((const float4*)xp)[0], ((const float4*)xp)[1]);
        a[mt][1] = pack8(((const float4*)(xp + 32))[0], ((const float4*)(xp + 32))[1]);
        const uint16_t* gp = XG + (size_t)n * 2048 + b * 64 + q8;
        a[mt][2] = *(const bf16x8*)gp;
        a[mt][3] = *(const bf16x8*)(gp + 32);
    }

    f32x4 accg[2][4], accs[2][4];
#pragma unroll
    for (int mt = 0; mt < 2; ++mt)
#pragma unroll
        for (int j = 0; j < 4; ++j) {
            accg[mt][j] = (f32x4){0.f, 0.f, 0.f, 0.f};
            accs[mt][j] = (f32x4){0.f, 0.f, 0.f, 0.f};
        }

    __syncthreads();

#pragma unroll
    for (int ks = 0; ks < 4; ++ks) {
        bf16x8 bw[4];
#pragma unroll
        for (int j = 0; j < 4; ++j)
            bw[j] = *(const bf16x8*)&Ws[w][j * 16 + l15][ks * 32 + q8];
#pragma unroll
        for (int mt = 0; mt < 2; ++mt)
#pragma unroll
            for (int j = 0; j < 4; ++j)
                accg[mt][j] = __builtin_amdgcn_mfma_f32_16x16x32_bf16(a[mt][ks], bw[j], accg[mt][j], 0, 0, 0);
        if (ks < 2) {
            bf16x8 bl[4];
#pragma unroll
            for (int j = 0; j < 4; ++j)
                bl[j] = *(const bf16x8*)&Lws[j * 16 + l15][ks * 32 + q8];
#pragma unroll
            for (int mt = 0; mt < 2; ++mt)
#pragma unroll
                for (int j = 0; j < 4; ++j)
                    accs[mt][j] = __builtin_amdgcn_mfma_f32_16x16x32_bf16(a[mt][ks], bl[j], accs[mt][j], 0, 0, 0);
        }
    }

    // epilogue: C/D layout col=lane&15 (=o within tile), row=quad*4+reg (=b)
    const float sc = scale[n];
#pragma unroll
    for (int j = 0; j < 4; ++j) {
        const int o = j * 16 + l15;
        const float bn = biasn[(size_t)n * 64 + o];
        const float lb = lin_b[o];
#pragma unroll
        for (int mt = 0; mt < 2; ++mt)
#pragma unroll
            for (int r = 0; r < 4; ++r) {
                const int b = mt * 16 + (lane >> 4) * 4 + r;
                const float gg = accg[mt][j][r] + bn;
                const float xs = sc * accs[mt][j][r] + lb;
                out[((size_t)b * Ndim + n) * 64 + o] = gg + xs / (1.f + __expf(-xs));
            }
    }
}

// ---------------------------------------------------------------------------
extern "C" void kernel_launch(void* const* d_in, const int* in_sizes, int n_in,
                              void* d_out, int out_size, void* d_ws, size_t ws_size,
                              hipStream_t stream) {
    const float* x         = (const float*)d_in[0];
    const float* E         = (const float*)d_in[1];
    const float* pool      = (const float*)d_in[2];
    const float* bias_pool = (const float*)d_in[3];
    const float* lin_w     = (const float*)d_in[4];
    const float* lin_b     = (const float*)d_in[5];
    const float* adj       = (const float*)d_in[6];
    float* out = (float*)d_out;

    uint8_t* ws = (uint8_t*)d_ws;
    uint16_t* A     = (uint16_t*)(ws);                 // 4096*4096*2  = 32 MiB
    uint16_t* Xtt   = (uint16_t*)(ws + 33554432);      // 2048*4096*2  = 16 MiB
    uint16_t* XG    = (uint16_t*)(ws + 50331648);      // 4096*2048*2  = 16 MiB
    uint16_t* Wt    = (uint16_t*)(ws + 67108864);      // 4096*8192*2  = 64 MiB
    float*    biasn = (float*)   (ws + 134217728);     // 4096*64*4    = 1 MiB
    float*    sd    = (float*)   (ws + 135266304);     // 16 KiB
    float*    scale = (float*)   (ws + 135282688);     // 16 KiB

    k1_dyn_adj<<<dim3(256), dim3(256), 0, stream>>>(E, A);
    k2_transpose<<<dim3(64, 32), dim3(256), 0, stream>>>(x, Xtt);
    k4a_rowsum<<<dim3(4096), dim3(256), 0, stream>>>(adj, sd, scale);
    k4b_scale<<<dim3(256), dim3(256), 0, stream>>>(adj, sd, scale);
    k5_wgen<<<dim3(512), dim3(256), 0, stream>>>(E, pool, bias_pool, Wt, biasn);
    k3_gemm<<<dim3(16, 32), dim3(256), 0, stream>>>(A, Xtt, XG);
    k6_gconv<<<dim3(1024), dim3(256), 0, stream>>>(x, XG, Wt, biasn, scale, lin_w, lin_b, out);
}